// Round 7
// baseline (90.497 us; speedup 1.0000x reference)
//
#include <hip/hip_runtime.h>

// CACE edge-basis -> segment-sum -> invariant contraction.
// v7: 4 independent single-wave node-lanes per 256-thread workgroup
//     (2500 workgroups instead of 10000 1-wave workgroups), ZERO s_barrier:
//     intra-wave LDS producer->consumer ordered by s_waitcnt lgkmcnt(0).
//     Keeps v6's channel factorization: A = wd_j*(W0i*S0 + W1i*S1),
//     Sz[r,a] accumulated per wave; deg-loop unrolled x2.

#define NN    10000
#define NE    100000
#define NRBF  8
#define NANG  20
#define NCHAN 9
#define CAP   64           // 1 lane per edge; Poisson(10) tail beyond 64 ~ 1e-30
#define BROW  28           // LDS row: rad[0..8) ang[8..28); 112B, 16B-aligned
#define NODES_PER_BLK 4
#define INV_CUT  (1.0f/5.5f)
#define PI_F     3.14159265358979323846f
#define RAD_NORM 0.6030226891555273f   // sqrt(2/5.5)

// wave-local "barrier": drain this wave's LDS ops; compiler may not reorder
#define WSYNC() asm volatile("s_waitcnt lgkmcnt(0)" ::: "memory")

__launch_bounds__(256, 4)
__global__ void scatter_k(const int* __restrict__ an, const int* __restrict__ ei,
                          int* __restrict__ cnt, int* __restrict__ lst) {
    int e = blockIdx.x * blockDim.x + threadIdx.x;
    if (e >= NE) return;
    int src = ei[e];
    int dst = ei[NE + e];
    int zs  = an[src];                       // L2-hot 40KB table
    int pos = atomicAdd(&cnt[dst], 1);
    if (pos < CAP) lst[dst * CAP + pos] = e | (zs << 20);   // eid < 2^17
}

__launch_bounds__(256, 4)
__global__ void node_k(const int* __restrict__ an, const float* __restrict__ elen,
                       const float* __restrict__ evec, const float* __restrict__ W,
                       const int* __restrict__ cnt, const int* __restrict__ lst,
                       float* __restrict__ out)
{
    __shared__ float sB[NODES_PER_BLK * CAP * BROW];   // 28 KB

    const int tid  = threadIdx.x;
    const int w    = tid >> 6;                 // wave slot 0..3
    const int lane = tid & 63;
    const int n    = blockIdx.x * NODES_PER_BLK + w;   // 2500*4 = 10000 exact

    float* Bw = &sB[w * CAP * BROW];           // this wave's private slice
    float* sA = Bw;                            // aliased after accumulate

    int deg = cnt[n]; if (deg > CAP) deg = CAP;
    const int zd = an[n];                      // wave-uniform
    const float W0=W[0], W1=W[1], W2=W[2], W3=W[3], W4=W[4], W5=W[5];

    // ---- lane e: rad+ang basis for edge e -> LDS row ----
    int zsv = 0;
    if (lane < deg) {
        const int v   = lst[n * CAP + lane];
        const int eid = v & 0xFFFFF;
        zsv = v >> 20;

        const float r  = elen[eid];
        const float vx = evec[3*eid+0], vy = evec[3*eid+1], vz = evec[3*eid+2];
        const float inv = rsqrtf(vx*vx + vy*vy + vz*vz);
        const float x = vx*inv, y = vy*inv, z = vz*inv;

        // radial: sin(k*pi*u) via Chebyshev recurrence, k=1..8
        const float u  = r * INV_CUT;
        const float u2 = u*u, u6 = u2*u2*u2;
        const float fc = (u < 1.0f) ? (1.0f - 28.0f*u6 + 48.0f*u6*u - 21.0f*u6*u2)
                                    : 0.0f;
        const float scale = RAD_NORM * fc / r;
        float s1, c1;
        sincosf(PI_F * u, &s1, &c1);
        const float twoc = 2.0f * c1;
        float sp = 0.0f, s = s1;
        float rad[8];
        #pragma unroll
        for (int k = 0; k < 8; ++k) {
            rad[k] = scale * s;
            const float sn = twoc * s - sp;
            sp = s; s = sn;
        }

        const float xx = x*x, xy = x*y, xz = x*z, yy = y*y, yz = y*z, zz = z*z;
        float* B = &Bw[lane * BROW];
        *(float4*)&B[0]  = make_float4(rad[0], rad[1], rad[2], rad[3]);
        *(float4*)&B[4]  = make_float4(rad[4], rad[5], rad[6], rad[7]);
        *(float4*)&B[8]  = make_float4(1.0f, x, y, z);
        *(float4*)&B[12] = make_float4(xx, xy, xz, yy);
        *(float4*)&B[16] = make_float4(yz, zz, x*xx, y*xx);
        *(float4*)&B[20] = make_float4(z*xx, x*yy, x*yz, x*zz);
        *(float4*)&B[24] = make_float4(y*yy, z*yy, y*zz, z*zz);
    }
    const unsigned long long zmask = __ballot(zsv != 0);   // per-wave
    WSYNC();   // all this wave's LDS writes visible to all its lanes

    // ---- accumulate Sz[r,a]: lane owns (r0, a0-tiers a0, 8+a0, 16+a0<20) ----
    const int r0 = lane & 7;
    const int a0 = lane >> 3;
    float s00=0.f, s01=0.f, s02=0.f;   // S0 accs (3 a-tiers)
    float s10=0.f, s11=0.f, s12=0.f;   // S1 accs

    int e = 0;
    for (; e + 1 < deg; e += 2) {
        const float* Ba = &Bw[e * BROW];
        const float* Bb = &Bw[(e+1) * BROW];
        const float z1a = (float)((zmask >> e) & 1ULL);
        const float z1b = (float)((zmask >> (e+1)) & 1ULL);
        const float z0a = 1.0f - z1a, z0b = 1.0f - z1b;
        const float rda = Ba[r0],      rdb = Bb[r0];
        const float v0a = rda * Ba[8 + a0],  v0b = rdb * Bb[8 + a0];
        const float v1a = rda * Ba[16 + a0], v1b = rdb * Bb[16 + a0];
        s00 = fmaf(v0a, z0a, s00); s10 = fmaf(v0a, z1a, s10);
        s01 = fmaf(v1a, z0a, s01); s11 = fmaf(v1a, z1a, s11);
        s00 = fmaf(v0b, z0b, s00); s10 = fmaf(v0b, z1b, s10);
        s01 = fmaf(v1b, z0b, s01); s11 = fmaf(v1b, z1b, s11);
        if (lane < 32) {
            const float v2a = rda * Ba[24 + a0], v2b = rdb * Bb[24 + a0];
            s02 = fmaf(v2a, z0a, s02); s12 = fmaf(v2a, z1a, s12);
            s02 = fmaf(v2b, z0b, s02); s12 = fmaf(v2b, z1b, s12);
        }
    }
    if (e < deg) {
        const float* B = &Bw[e * BROW];
        const float z1 = (float)((zmask >> e) & 1ULL);
        const float z0 = 1.0f - z1;
        const float rd = B[r0];
        const float v0 = rd * B[8 + a0];
        const float v1 = rd * B[16 + a0];
        s00 = fmaf(v0, z0, s00); s10 = fmaf(v0, z1, s10);
        s01 = fmaf(v1, z0, s01); s11 = fmaf(v1, z1, s11);
        if (lane < 32) {
            const float v2 = rd * B[24 + a0];
            s02 = fmaf(v2, z0, s02); s12 = fmaf(v2, z1, s12);
        }
    }
    WSYNC();   // all sB reads landed before slice is overwritten as sA

    // ---- expand A[r][a][c] = (W[0,i]*S0 + W[1,i]*S1) * wd[j], c=i*3+j ----
    const float wd0 = zd ? W3 : W0, wd1 = zd ? W4 : W1, wd2 = zd ? W5 : W2;
    {
        const float t00 = W0*s00 + W3*s10, t01 = W1*s00 + W4*s10, t02 = W2*s00 + W5*s10;
        float* Ap = &sA[r0*180 + a0*9];
        Ap[0]=t00*wd0; Ap[1]=t00*wd1; Ap[2]=t00*wd2;
        Ap[3]=t01*wd0; Ap[4]=t01*wd1; Ap[5]=t01*wd2;
        Ap[6]=t02*wd0; Ap[7]=t02*wd1; Ap[8]=t02*wd2;
    }
    {
        const float t10 = W0*s01 + W3*s11, t11 = W1*s01 + W4*s11, t12 = W2*s01 + W5*s11;
        float* Ap = &sA[r0*180 + (8 + a0)*9];
        Ap[0]=t10*wd0; Ap[1]=t10*wd1; Ap[2]=t10*wd2;
        Ap[3]=t11*wd0; Ap[4]=t11*wd1; Ap[5]=t11*wd2;
        Ap[6]=t12*wd0; Ap[7]=t12*wd1; Ap[8]=t12*wd2;
    }
    if (lane < 32) {
        const float t20 = W0*s02 + W3*s12, t21 = W1*s02 + W4*s12, t22 = W2*s02 + W5*s12;
        float* Ap = &sA[r0*180 + (16 + a0)*9];
        Ap[0]=t20*wd0; Ap[1]=t20*wd1; Ap[2]=t20*wd2;
        Ap[3]=t21*wd0; Ap[4]=t21*wd1; Ap[5]=t21*wd2;
        Ap[6]=t22*wd0; Ap[7]=t22*wd1; Ap[8]=t22*wd2;
    }
    WSYNC();   // expansion writes visible before contraction reads

    // ---- contraction B[n,r,l,c]; A[r][a][c] at sA[r*180 + a*9 + c] ----
    for (int o = lane; o < NRBF*4*NCHAN; o += 64) {
        const int r = o / 36, rem = o - r*36, l = rem / 9, c = rem - (rem/9)*9;
        const float* Ar = &sA[r * 180 + c];
        float val;
        if (l == 0) {
            val = Ar[0];
        } else if (l == 1) {         // a=1..3, pref {1,1,1}
            const float v1 = Ar[9], v2 = Ar[18], v3 = Ar[27];
            val = v1*v1 + v2*v2 + v3*v3;
        } else if (l == 2) {         // a=4..9, pref {1,2,2,1,2,1}
            const float v0=Ar[36], v1=Ar[45], v2=Ar[54],
                        v3=Ar[63], v4=Ar[72], v5=Ar[81];
            val = v0*v0 + 2.0f*(v1*v1 + v2*v2 + v4*v4) + v3*v3 + v5*v5;
        } else {                     // a=10..19, pref {1,3,3,3,6,3,1,3,3,1}
            const float w0=Ar[90],  w1=Ar[99],  w2=Ar[108], w3=Ar[117], w4=Ar[126];
            const float w5=Ar[135], w6=Ar[144], w7=Ar[153], w8=Ar[162], w9=Ar[171];
            val = w0*w0 + w6*w6 + w9*w9
                + 3.0f*(w1*w1 + w2*w2 + w3*w3 + w5*w5 + w7*w7 + w8*w8)
                + 6.0f*w4*w4;
        }
        out[n * (NRBF*4*NCHAN) + o] = val;
    }
}

extern "C" void kernel_launch(void* const* d_in, const int* in_sizes, int n_in,
                              void* d_out, int out_size, void* d_ws, size_t ws_size,
                              hipStream_t stream) {
    // inputs: 0 positions (unused), 1 atomic_numbers, 2 edge_index,
    //         3 edge_lengths, 4 edge_vectors, 5 W_embed
    const int*   an   = (const int*)d_in[1];
    const int*   ei   = (const int*)d_in[2];
    const float* elen = (const float*)d_in[3];
    const float* evec = (const float*)d_in[4];
    const float* W    = (const float*)d_in[5];
    float* out = (float*)d_out;

    // ws layout: cnt[NN] | lst[NN*CAP]  (~2.6 MB)
    int* cnt = (int*)d_ws;
    int* lst = cnt + NN;

    hipMemsetAsync(cnt, 0, NN * sizeof(int), stream);
    scatter_k<<<(NE + 255)/256, 256, 0, stream>>>(an, ei, cnt, lst);
    node_k<<<NN / NODES_PER_BLK, 256, 0, stream>>>(an, elen, evec, W, cnt, lst, out);
}